// Round 19
// baseline (137.243 us; speedup 1.0000x reference)
//
#include <hip/hip_runtime.h>
#include <hip/hip_bf16.h>

typedef _Float16 h8 __attribute__((ext_vector_type(8)));
typedef float f4 __attribute__((ext_vector_type(4)));

#define T_ 4
#define B_ 8
#define N_ 512
#define C_ 512
#define H_ 8
#define D_ 64
#define BNR 4096
#define EPSf 1e-5f
#define F16_MIN_NORM 6.1035156e-05f
#define INV4096 0.000244140625f

// ---- merged preprocessing: x-split-pack (blocks 0..4095) + W-pack (4096..4607) ----
__global__ __launch_bounds__(256)
void pack_all(const float* __restrict__ in, _Float16* __restrict__ h1,
              _Float16* __restrict__ h2,
              const float* __restrict__ Wq, const float* __restrict__ Wk,
              const float* __restrict__ Wv, const float* __restrict__ Wp,
              _Float16* q1, _Float16* q2, _Float16* k1, _Float16* k2,
              _Float16* v1, _Float16* v2, _Float16* p1, _Float16* p2)
{
    if (blockIdx.x < 4096) {
        // A1p/A2p[rt][t][ks][lane][8]: lane l holds x[t][rt*16+(l&15)][ks*32+(l>>4)*8 ..+8]
        const int gid = blockIdx.x * 256 + threadIdx.x;    // 1048576 h8-groups
        const int lane = gid & 63;
        const int ks = (gid >> 6) & 15;
        const int t = (gid >> 10) & 3;
        const int rt = gid >> 12;
        const int row = rt * 16 + (lane & 15);
        const size_t src = ((size_t)t * BNR + row) * C_ + ks * 32 + (lane >> 4) * 8;
        const float4 x0 = *reinterpret_cast<const float4*>(in + src);
        const float4 x1 = *reinterpret_cast<const float4*>(in + src + 4);
        h8 a, b;
        #pragma unroll
        for (int j = 0; j < 8; ++j) {
            const float xv = (j < 4) ? (&x0.x)[j] : (&x1.x)[j - 4];
            const float hi = (fabsf(xv) >= F16_MIN_NORM) ? xv : 0.0f;
            const _Float16 h = (_Float16)hi;
            const float r = (xv - (float)h) * 4096.0f;
            a[j] = h; b[j] = (_Float16)r;
        }
        *reinterpret_cast<h8*>(h1 + (size_t)gid * 8) = a;
        *reinterpret_cast<h8*>(h2 + (size_t)gid * 8) = b;
    } else {
        const int g = (blockIdx.x - 4096) * 256 + threadIdx.x;   // 131072
        const int br = g >> 15;
        const int gid = g & 32767;
        const float* W = (br == 0) ? Wq : (br == 1) ? Wk : (br == 2) ? Wv : Wp;
        _Float16* Wp1 = (br == 0) ? q1 : (br == 1) ? k1 : (br == 2) ? v1 : p1;
        _Float16* Wp2 = (br == 0) ? q2 : (br == 1) ? k2 : (br == 2) ? v2 : p2;
        const int lane = gid & 63;
        const int ni = (gid >> 6) & 3;
        const int ks = (gid >> 8) & 15;
        const int ct = gid >> 12;
        const int col = ct * 64 + ni * 16 + (lane & 15);
        const int k = ks * 32 + (lane >> 4) * 8;
        const float* src = W + (size_t)col * C_ + k;
        h8 a, b;
        #pragma unroll
        for (int j = 0; j < 8; ++j) {
            const float xv = src[j];
            const float hi = (fabsf(xv) >= F16_MIN_NORM) ? xv : 0.0f;
            const _Float16 h = (_Float16)hi;
            const float r = (xv - (float)h) * 4096.0f;
            a[j] = h; b[j] = (_Float16)r;
        }
        *reinterpret_cast<h8*>(Wp1 + (size_t)gid * 8) = a;
        *reinterpret_cast<h8*>(Wp2 + (size_t)gid * 8) = b;
    }
}

// ---- gemm3: T4 structure + DEPTH-2 A register-prefetch ----
// At barrier(ks) the VMEM queue is [A(ks)x4, gll(ks), A(ks+1)x4]; vmcnt(4)
// retires A(ks)+gll(ks) (both consumed this step), A(ks+1) stays in flight.
// A loads now get ~2 MFMA-blocks (~1900 cyc) of shadow -> covers HBM ~900.
__global__ __launch_bounds__(512, 4)
void gemm3_bn_lif(const _Float16* __restrict__ A1p, const _Float16* __restrict__ A2p,
                  const _Float16* __restrict__ Wq1, const _Float16* __restrict__ Wq2,
                  const _Float16* __restrict__ Wk1, const _Float16* __restrict__ Wk2,
                  const _Float16* __restrict__ Wv1, const _Float16* __restrict__ Wv2,
                  const float* __restrict__ biq, const float* __restrict__ gaq,
                  const float* __restrict__ beq, const float* __restrict__ meq,
                  const float* __restrict__ rvq,
                  const float* __restrict__ bik, const float* __restrict__ gak,
                  const float* __restrict__ bek, const float* __restrict__ mek,
                  const float* __restrict__ rvk,
                  const float* __restrict__ biv, const float* __restrict__ gav,
                  const float* __restrict__ bev, const float* __restrict__ mev,
                  const float* __restrict__ rvv,
                  _Float16* __restrict__ oq, _Float16* __restrict__ ok,
                  _Float16* __restrict__ ov)
{
    __shared__ __align__(16) char wsm[16384];           // 2 x 8KB W dbuf; reused as v-state
    const int id = blockIdx.x;                          // 1536 blocks
    const int xcd = id & 7;
    const int j = id >> 3;                              // 0..191
    const int br = j % 3;
    const int rest = j / 3;                             // 0..63
    const int bt = xcd * 8 + (rest & 7);                // 0..63
    const int ct = rest >> 3;                           // 0..7

    const _Float16* W1 = (br == 0) ? Wq1 : (br == 1) ? Wk1 : Wv1;
    const _Float16* W2 = (br == 0) ? Wq2 : (br == 1) ? Wk2 : Wv2;
    const float* bias = (br == 0) ? biq : (br == 1) ? bik : biv;
    const float* gam  = (br == 0) ? gaq : (br == 1) ? gak : gav;
    const float* bet  = (br == 0) ? beq : (br == 1) ? bek : bev;
    const float* mea  = (br == 0) ? meq : (br == 1) ? mek : mev;
    const float* rva  = (br == 0) ? rvq : (br == 1) ? rvk : rvv;
    _Float16* out = (br == 0) ? oq : (br == 1) ? ok : ov;

    const int tid = threadIdx.x;
    const int wave = tid >> 6, lane = tid & 63;
    const int tp = wave & 1, wr = wave >> 1;
    const int rt = bt * 4 + wr;
    const int row0 = bt * 64, col0 = ct * 64;
    const int lr = lane & 15, lk = lane >> 4;

    f4 accA[2][4], accB[2][4];
    #pragma unroll
    for (int ti = 0; ti < 2; ++ti)
        #pragma unroll
        for (int ni = 0; ni < 4; ++ni) { accA[ti][ni] = (f4)0.0f; accB[ti][ni] = (f4)0.0f; }

    const _Float16* aB1 = A1p + (size_t)rt * 32768 + lane * 8;
    const _Float16* aB2 = A2p + (size_t)rt * 32768 + lane * 8;
    const int s_ = wave >> 2, q_ = wave & 3;
    const _Float16* wsrc = (s_ ? W2 : W1) + (size_t)ct * 32768 + q_ * 512 + lane * 8;
    const int wdoff = s_ * 4096 + q_ * 1024;

    auto stageW = [&](int ks, int b) {
        __builtin_amdgcn_global_load_lds(
            (const __attribute__((address_space(1))) unsigned int*)(wsrc + ks * 2048),
            (__attribute__((address_space(3))) unsigned int*)(wsm + b * 8192 + wdoff),
            16, 0, 0);
    };

    // prologue: gll(0) first, then A(0) and A(1) fragment loads
    stageW(0, 0);
    h8 a1c[2], a2c[2], a1n[2], a2n[2];
    #pragma unroll
    for (int ti = 0; ti < 2; ++ti) {
        const int t = tp * 2 + ti;
        a1c[ti] = *reinterpret_cast<const h8*>(aB1 + (t * 16 + 0) * 512);
        a2c[ti] = *reinterpret_cast<const h8*>(aB2 + (t * 16 + 0) * 512);
        a1n[ti] = *reinterpret_cast<const h8*>(aB1 + (t * 16 + 1) * 512);
        a2n[ti] = *reinterpret_cast<const h8*>(aB2 + (t * 16 + 1) * 512);
    }
    #pragma unroll
    for (int ks = 0; ks < 16; ++ks) {
        const int buf = ks & 1;
        asm volatile("s_waitcnt vmcnt(4)" ::: "memory");
        __builtin_amdgcn_s_barrier();
        __builtin_amdgcn_sched_barrier(0);
        h8 a1nn[2], a2nn[2];
        if (ks < 15) stageW(ks + 1, buf ^ 1);           // post-barrier: W-ring safe
        if (ks < 14) {
            #pragma unroll
            for (int ti = 0; ti < 2; ++ti) {            // prefetch A[ks+2]
                const int t = tp * 2 + ti;
                a1nn[ti] = *reinterpret_cast<const h8*>(aB1 + (t * 16 + ks + 2) * 512);
                a2nn[ti] = *reinterpret_cast<const h8*>(aB2 + (t * 16 + ks + 2) * 512);
            }
        }
        const char* wb = wsm + buf * 8192;
        #pragma unroll
        for (int ni = 0; ni < 4; ++ni) {
            const h8 wf1 = *reinterpret_cast<const h8*>(wb + ni * 1024 + lane * 16);
            const h8 wf2 = *reinterpret_cast<const h8*>(wb + 4096 + ni * 1024 + lane * 16);
            #pragma unroll
            for (int ti = 0; ti < 2; ++ti) {
                accA[ti][ni] = __builtin_amdgcn_mfma_f32_16x16x32_f16(a1c[ti], wf1, accA[ti][ni], 0, 0, 0);
                accB[ti][ni] = __builtin_amdgcn_mfma_f32_16x16x32_f16(a1c[ti], wf2, accB[ti][ni], 0, 0, 0);
                accB[ti][ni] = __builtin_amdgcn_mfma_f32_16x16x32_f16(a2c[ti], wf1, accB[ti][ni], 0, 0, 0);
            }
        }
        #pragma unroll
        for (int ti = 0; ti < 2; ++ti) {
            a1c[ti] = a1n[ti]; a2c[ti] = a2n[ti];
            if (ks < 14) { a1n[ti] = a1nn[ti]; a2n[ti] = a2nn[ti]; }
        }
    }

    float* vst = (float*)wsm;
    float sc[4], bi[4], mn[4], be[4];
    #pragma unroll
    for (int ni = 0; ni < 4; ++ni) {
        const int c = col0 + ni * 16 + lr;
        sc[ni] = gam[c] * (1.0f / sqrtf(rva[c] + EPSf));
        bi[ni] = bias[c]; mn[ni] = mea[c]; be[ni] = bet[c];
    }
    __syncthreads();
    if (tp == 0) {
        #pragma unroll
        for (int ni = 0; ni < 4; ++ni)
            #pragma unroll
            for (int r = 0; r < 4; ++r) {
                const int rl = wr * 16 + lk * 4 + r;
                const int bn = row0 + rl;
                float vm = 0.0f;
                #pragma unroll
                for (int ti = 0; ti < 2; ++ti) {        // t = 0,1
                    const float res = accA[ti][ni][r] + INV4096 * accB[ti][ni][r];
                    const float y = ((res + bi[ni]) - mn[ni]) * sc[ni] + be[ni];
                    vm = vm + (y - vm) * 0.5f;
                    const float s = (vm >= 1.0f) ? 1.0f : 0.0f;
                    vm = (s != 0.0f) ? 0.0f : vm;
                    const int b = bn >> 9, n = bn & 511;
                    out[((((size_t)ti * B_ + b) * H_ + ct) * N_ + n) * D_ + ni * 16 + lr] =
                        (_Float16)s;
                }
                vst[rl * 64 + ni * 16 + lr] = vm;
            }
    }
    __syncthreads();
    if (tp == 1) {
        #pragma unroll
        for (int ni = 0; ni < 4; ++ni)
            #pragma unroll
            for (int r = 0; r < 4; ++r) {
                const int rl = wr * 16 + lk * 4 + r;
                const int bn = row0 + rl;
                float vm = vst[rl * 64 + ni * 16 + lr];
                #pragma unroll
                for (int ti = 0; ti < 2; ++ti) {        // t = 2,3
                    const float res = accA[ti][ni][r] + INV4096 * accB[ti][ni][r];
                    const float y = ((res + bi[ni]) - mn[ni]) * sc[ni] + be[ni];
                    vm = vm + (y - vm) * 0.5f;
                    const float s = (vm >= 1.0f) ? 1.0f : 0.0f;
                    vm = (s != 0.0f) ? 0.0f : vm;
                    const int b = bn >> 9, n = bn & 511;
                    out[((((size_t)(2 + ti) * B_ + b) * H_ + ct) * N_ + n) * D_ + ni * 16 + lr] =
                        (_Float16)s;
                }
            }
    }
}

// ---- p-GEMM: r15 proven version (512 thr, per-ks W stage, vmcnt(2)) ----
__global__ __launch_bounds__(512, 4)
void gemm_p_bn_lif(const _Float16* __restrict__ A1p,
                   const _Float16* __restrict__ Wp1, const _Float16* __restrict__ Wp2,
                   const float* __restrict__ bias, const float* __restrict__ gam,
                   const float* __restrict__ bet, const float* __restrict__ mea,
                   const float* __restrict__ rva, float* __restrict__ out_plain)
{
    __shared__ __align__(16) char wsm[16384];
    const int id = blockIdx.x;
    const int bt = (id & 7) * 8 + ((id >> 3) & 7);
    const int ct = id >> 6;
    const int tid = threadIdx.x;
    const int wave = tid >> 6, lane = tid & 63;
    const int tp = wave & 1, wr = wave >> 1;
    const int rt = bt * 4 + wr;
    const int row0 = bt * 64, col0 = ct * 64;
    const int lr = lane & 15, lk = lane >> 4;

    f4 accA[2][4], accB[2][4];
    #pragma unroll
    for (int ti = 0; ti < 2; ++ti)
        #pragma unroll
        for (int ni = 0; ni < 4; ++ni) { accA[ti][ni] = (f4)0.0f; accB[ti][ni] = (f4)0.0f; }

    const _Float16* aB1 = A1p + (size_t)rt * 32768 + lane * 8;
    const int s_ = wave >> 2, q_ = wave & 3;
    const _Float16* wsrc = (s_ ? Wp2 : Wp1) + (size_t)ct * 32768 + q_ * 512 + lane * 8;
    const int wdoff = s_ * 4096 + q_ * 1024;

    auto stageW = [&](int ks, int b) {
        __builtin_amdgcn_global_load_lds(
            (const __attribute__((address_space(1))) unsigned int*)(wsrc + ks * 2048),
            (__attribute__((address_space(3))) unsigned int*)(wsm + b * 8192 + wdoff),
            16, 0, 0);
    };

    stageW(0, 0);
    h8 a1c[2];
    #pragma unroll
    for (int ti = 0; ti < 2; ++ti) {
        const int t = tp * 2 + ti;
        a1c[ti] = *reinterpret_cast<const h8*>(aB1 + (t * 16 + 0) * 512);
    }
    #pragma unroll
    for (int ks = 0; ks < 16; ++ks) {
        const int buf = ks & 1;
        asm volatile("s_waitcnt vmcnt(2)" ::: "memory");
        __builtin_amdgcn_s_barrier();
        __builtin_amdgcn_sched_barrier(0);
        h8 a1n[2];
        if (ks < 15) {
            stageW(ks + 1, buf ^ 1);
            #pragma unroll
            for (int ti = 0; ti < 2; ++ti) {
                const int t = tp * 2 + ti;
                a1n[ti] = *reinterpret_cast<const h8*>(aB1 + (t * 16 + ks + 1) * 512);
            }
        }
        const char* wb = wsm + buf * 8192;
        #pragma unroll
        for (int ni = 0; ni < 4; ++ni) {
            const h8 wf1 = *reinterpret_cast<const h8*>(wb + ni * 1024 + lane * 16);
            const h8 wf2 = *reinterpret_cast<const h8*>(wb + 4096 + ni * 1024 + lane * 16);
            #pragma unroll
            for (int ti = 0; ti < 2; ++ti) {
                accA[ti][ni] = __builtin_amdgcn_mfma_f32_16x16x32_f16(a1c[ti], wf1, accA[ti][ni], 0, 0, 0);
                accB[ti][ni] = __builtin_amdgcn_mfma_f32_16x16x32_f16(a1c[ti], wf2, accB[ti][ni], 0, 0, 0);
            }
        }
        if (ks < 15) {
            #pragma unroll
            for (int ti = 0; ti < 2; ++ti) a1c[ti] = a1n[ti];
        }
    }

    float* vst = (float*)wsm;
    float sc[4], bi[4], mn[4], be[4];
    #pragma unroll
    for (int ni = 0; ni < 4; ++ni) {
        const int c = col0 + ni * 16 + lr;
        sc[ni] = gam[c] * (1.0f / sqrtf(rva[c] + EPSf));
        bi[ni] = bias[c]; mn[ni] = mea[c]; be[ni] = bet[c];
    }
    __syncthreads();
    if (tp == 0) {
        #pragma unroll
        for (int ni = 0; ni < 4; ++ni)
            #pragma unroll
            for (int r = 0; r < 4; ++r) {
                const int rl = wr * 16 + lk * 4 + r;
                const int bn = row0 + rl;
                float vm = 0.0f;
                #pragma unroll
                for (int ti = 0; ti < 2; ++ti) {        // t = 0,1
                    const float res = accA[ti][ni][r] + INV4096 * accB[ti][ni][r];
                    const float y = ((res + bi[ni]) - mn[ni]) * sc[ni] + be[ni];
                    vm = vm + (y - vm) * 0.5f;
                    const float s = (vm >= 1.0f) ? 1.0f : 0.0f;
                    vm = (s != 0.0f) ? 0.0f : vm;
                    out_plain[((size_t)ti * BNR + bn) * C_ + col0 + ni * 16 + lr] = s;
                }
                vst[rl * 64 + ni * 16 + lr] = vm;
            }
    }
    __syncthreads();
    if (tp == 1) {
        #pragma unroll
        for (int ni = 0; ni < 4; ++ni)
            #pragma unroll
            for (int r = 0; r < 4; ++r) {
                const int rl = wr * 16 + lk * 4 + r;
                const int bn = row0 + rl;
                float vm = vst[rl * 64 + ni * 16 + lr];
                #pragma unroll
                for (int ti = 0; ti < 2; ++ti) {        // t = 2,3
                    const float res = accA[ti][ni][r] + INV4096 * accB[ti][ni][r];
                    const float y = ((res + bi[ni]) - mn[ni]) * sc[ni] + be[ni];
                    vm = vm + (y - vm) * 0.5f;
                    const float s = (vm >= 1.0f) ? 1.0f : 0.0f;
                    vm = (s != 0.0f) ? 0.0f : vm;
                    out_plain[((size_t)(2 + ti) * BNR + bn) * C_ + col0 + ni * 16 + lr] = s;
                }
            }
    }
}

// ---- ktv via MFMA: kvT[d2][d1] = sum_n v[n,d2]*k[n,d1], exact integers ----
__global__ __launch_bounds__(256)
void ktv_mfma(const _Float16* __restrict__ sk, const _Float16* __restrict__ sv,
              _Float16* __restrict__ kvT)
{
    __shared__ _Float16 kT[64][64];
    __shared__ _Float16 vT[64][64];
    const int tbh = blockIdx.x;
    const int tid = threadIdx.x;
    const int wv = tid >> 6, lane = tid & 63;
    const int lr = lane & 15, lk = lane >> 4;
    const size_t base = (size_t)tbh * N_ * D_;

    f4 acc[4];
    #pragma unroll
    for (int ni = 0; ni < 4; ++ni) acc[ni] = (f4)0.0f;

    for (int n0 = 0; n0 < N_; n0 += 64) {
        __syncthreads();
        #pragma unroll
        for (int p = 0; p < 2; ++p) {
            const int idx = p * 256 + tid;
            const int n = idx >> 3, d0 = (idx & 7) * 8;
            const h8 kv_ = *reinterpret_cast<const h8*>(&sk[base + (size_t)(n0 + n) * D_ + d0]);
            const h8 vv_ = *reinterpret_cast<const h8*>(&sv[base + (size_t)(n0 + n) * D_ + d0]);
            #pragma unroll
            for (int j = 0; j < 8; ++j) {
                const int d = d0 + j;
                const int nsw = (((n >> 3) ^ (d & 7)) << 3) | (n & 7);
                kT[d][nsw] = kv_[j];
                vT[d][nsw] = vv_[j];
            }
        }
        __syncthreads();
        #pragma unroll
        for (int ks2 = 0; ks2 < 2; ++ks2) {
            const int g0 = ks2 * 4 + lk;
            const int d2 = wv * 16 + lr;
            const h8 av = *reinterpret_cast<const h8*>(&vT[d2][(g0 ^ (d2 & 7)) << 3]);
            #pragma unroll
            for (int ni = 0; ni < 4; ++ni) {
                const int d1 = ni * 16 + lr;
                const h8 bk = *reinterpret_cast<const h8*>(&kT[d1][(g0 ^ (d1 & 7)) << 3]);
                acc[ni] = __builtin_amdgcn_mfma_f32_16x16x32_f16(av, bk, acc[ni], 0, 0, 0);
            }
        }
    }
    _Float16* out = kvT + (size_t)tbh * 4096;
    #pragma unroll
    for (int ni = 0; ni < 4; ++ni)
        #pragma unroll
        for (int r = 0; r < 4; ++r) {
            const int d2 = wv * 16 + lk * 4 + r;
            const int d1 = ni * 16 + lr;
            out[d2 * 64 + d1] = (_Float16)acc[ni][r];
        }
}

// ---- o = 0.125 * q @ kv via MFMA (exact integer arith), fused attn-LIF ----
__global__ __launch_bounds__(256)
void qkv_mfma_lif(const _Float16* __restrict__ sq, const _Float16* __restrict__ kvT,
                  _Float16* __restrict__ osp)
{
    __shared__ __align__(16) char ot[8192];             // [64 rows][128B], swizzled
    const int nt = blockIdx.x, b = blockIdx.y, h = blockIdx.z;
    const int tid = threadIdx.x;
    const int wv = tid >> 6, lane = tid & 63;
    const int lr = lane & 15, lk = lane >> 4;
    const int n0 = nt * 64;

    f4 vst[4];
    #pragma unroll
    for (int ni = 0; ni < 4; ++ni) vst[ni] = (f4)0.0f;

    for (int t = 0; t < T_; ++t) {
        const int tbh = (t * B_ + b) * H_ + h;
        const _Float16* qb = sq + ((size_t)tbh * N_ + n0 + wv * 16 + lr) * D_;
        const h8 a0 = *reinterpret_cast<const h8*>(qb + lk * 8);
        const h8 a1 = *reinterpret_cast<const h8*>(qb + 32 + lk * 8);
        const _Float16* kb = kvT + (size_t)tbh * 4096 + lr * 64 + lk * 8;
        f4 acc[4];
        #pragma unroll
        for (int ni = 0; ni < 4; ++ni) {
            const _Float16* kbn = kb + ni * 1024;
            const h8 b0 = *reinterpret_cast<const h8*>(kbn);
            const h8 b1 = *reinterpret_cast<const h8*>(kbn + 32);
            f4 a = (f4)0.0f;
            a = __builtin_amdgcn_mfma_f32_16x16x32_f16(a0, b0, a, 0, 0, 0);
            a = __builtin_amdgcn_mfma_f32_16x16x32_f16(a1, b1, a, 0, 0, 0);
            acc[ni] = a;
        }
        #pragma unroll
        for (int ni = 0; ni < 4; ++ni)
            #pragma unroll
            for (int r = 0; r < 4; ++r) {
                const float y = 0.125f * acc[ni][r];    // exact
                float vv = vst[ni][r];
                vv = vv + (y - vv) * 0.5f;
                const float s = (vv >= 0.5f) ? 1.0f : 0.0f;
                vst[ni][r] = (s != 0.0f) ? 0.0f : vv;
                const int row = wv * 16 + lk * 4 + r;
                const int colb = (ni * 16 + lr) * 2;
                *(_Float16*)(ot + row * 128 + (colb ^ ((row & 7) << 4))) = (_Float16)s;
            }
        const int rt = b * 32 + nt * 4 + wv;
        #pragma unroll
        for (int ks1 = 0; ks1 < 2; ++ks1) {
            const int row = wv * 16 + lr;
            const int colb = ks1 * 64 + lk * 16;
            const h8 vvv = *reinterpret_cast<const h8*>(ot + row * 128 + (colb ^ ((row & 7) << 4)));
            *reinterpret_cast<h8*>(osp +
                ((((size_t)rt * 4 + t) * 16 + h * 2 + ks1) * 64 + lane) * 8) = vvv;
        }
    }
}

extern "C" void kernel_launch(void* const* d_in, const int* in_sizes, int n_in,
                              void* d_out, int out_size, void* d_ws, size_t ws_size,
                              hipStream_t stream)
{
    const float* x = (const float*)d_in[0];
    const float *W[4], *bia[4], *gam[4], *bet[4], *mea[4], *rva[4];
    for (int br = 0; br < 4; ++br) {
        W[br]   = (const float*)d_in[1 + 6 * br + 0];
        bia[br] = (const float*)d_in[1 + 6 * br + 1];
        gam[br] = (const float*)d_in[1 + 6 * br + 2];
        bet[br] = (const float*)d_in[1 + 6 * br + 3];
        mea[br] = (const float*)d_in[1 + 6 * br + 4];
        rva[br] = (const float*)d_in[1 + 6 * br + 5];
    }
    char* ws = (char*)d_ws;
    _Float16* x1 = (_Float16*)(ws + 0);
    _Float16* x2 = (_Float16*)(ws + 16777216);
    _Float16* sq = (_Float16*)(ws + 33554432);
    _Float16* sk = (_Float16*)(ws + 50331648);
    _Float16* sv = (_Float16*)(ws + 67108864);
    _Float16* w1[4], *w2[4];
    for (int br = 0; br < 4; ++br) {
        w1[br] = (_Float16*)(ws + 83886080 + (size_t)br * 1048576);
        w2[br] = (_Float16*)(ws + 83886080 + (size_t)br * 1048576 + 524288);
    }
    _Float16* kvT = (_Float16*)(ws + 16777216);  // aliases x2 (dead after gemm3)
    _Float16* osp = (_Float16*)(ws + 0);         // aliases x1 (dead after gemm3)

    dim3 blk(256);
    pack_all<<<dim3(4608), blk, 0, stream>>>(x, x1, x2,
        W[0], W[1], W[2], W[3],
        w1[0], w2[0], w1[1], w2[1], w1[2], w2[2], w1[3], w2[3]);

    gemm3_bn_lif<<<dim3(1536), dim3(512), 0, stream>>>(x1, x2,
        w1[0], w2[0], w1[1], w2[1], w1[2], w2[2],
        bia[0], gam[0], bet[0], mea[0], rva[0],
        bia[1], gam[1], bet[1], mea[1], rva[1],
        bia[2], gam[2], bet[2], mea[2], rva[2],
        sq, sk, sv);

    ktv_mfma<<<dim3(T_ * B_ * H_), blk, 0, stream>>>(sk, sv, kvT);
    qkv_mfma_lif<<<dim3(N_ / 64, B_, H_), blk, 0, stream>>>(sq, kvT, osp);

    gemm_p_bn_lif<<<dim3(512), dim3(512), 0, stream>>>(osp, w1[3], w2[3],
        bia[3], gam[3], bet[3], mea[3], rva[3], (float*)d_out);
}

// Round 20
// 133.938 us; speedup vs baseline: 1.0247x; 1.0247x over previous
//
#include <hip/hip_runtime.h>
#include <hip/hip_bf16.h>

typedef _Float16 h8 __attribute__((ext_vector_type(8)));
typedef float f4 __attribute__((ext_vector_type(4)));

#define T_ 4
#define B_ 8
#define N_ 512
#define C_ 512
#define H_ 8
#define D_ 64
#define BNR 4096
#define EPSf 1e-5f
#define F16_MIN_NORM 6.1035156e-05f
#define INV4096 0.000244140625f

// ---- merged preprocessing: x-split-pack (blocks 0..4095) + W-pack (4096..4607) ----
__global__ __launch_bounds__(256)
void pack_all(const float* __restrict__ in, _Float16* __restrict__ h1,
              _Float16* __restrict__ h2,
              const float* __restrict__ Wq, const float* __restrict__ Wk,
              const float* __restrict__ Wv, const float* __restrict__ Wp,
              _Float16* q1, _Float16* q2, _Float16* k1, _Float16* k2,
              _Float16* v1, _Float16* v2, _Float16* p1, _Float16* p2)
{
    if (blockIdx.x < 4096) {
        // A1p/A2p[rt][t][ks][lane][8]: lane l holds x[t][rt*16+(l&15)][ks*32+(l>>4)*8 ..+8]
        const int gid = blockIdx.x * 256 + threadIdx.x;    // 1048576 h8-groups
        const int lane = gid & 63;
        const int ks = (gid >> 6) & 15;
        const int t = (gid >> 10) & 3;
        const int rt = gid >> 12;
        const int row = rt * 16 + (lane & 15);
        const size_t src = ((size_t)t * BNR + row) * C_ + ks * 32 + (lane >> 4) * 8;
        const float4 x0 = *reinterpret_cast<const float4*>(in + src);
        const float4 x1 = *reinterpret_cast<const float4*>(in + src + 4);
        h8 a, b;
        #pragma unroll
        for (int j = 0; j < 8; ++j) {
            const float xv = (j < 4) ? (&x0.x)[j] : (&x1.x)[j - 4];
            const float hi = (fabsf(xv) >= F16_MIN_NORM) ? xv : 0.0f;
            const _Float16 h = (_Float16)hi;
            const float r = (xv - (float)h) * 4096.0f;
            a[j] = h; b[j] = (_Float16)r;
        }
        *reinterpret_cast<h8*>(h1 + (size_t)gid * 8) = a;
        *reinterpret_cast<h8*>(h2 + (size_t)gid * 8) = b;
    } else {
        const int g = (blockIdx.x - 4096) * 256 + threadIdx.x;   // 131072
        const int br = g >> 15;
        const int gid = g & 32767;
        const float* W = (br == 0) ? Wq : (br == 1) ? Wk : (br == 2) ? Wv : Wp;
        _Float16* Wp1 = (br == 0) ? q1 : (br == 1) ? k1 : (br == 2) ? v1 : p1;
        _Float16* Wp2 = (br == 0) ? q2 : (br == 1) ? k2 : (br == 2) ? v2 : p2;
        const int lane = gid & 63;
        const int ni = (gid >> 6) & 3;
        const int ks = (gid >> 8) & 15;
        const int ct = gid >> 12;
        const int col = ct * 64 + ni * 16 + (lane & 15);
        const int k = ks * 32 + (lane >> 4) * 8;
        const float* src = W + (size_t)col * C_ + k;
        h8 a, b;
        #pragma unroll
        for (int j = 0; j < 8; ++j) {
            const float xv = src[j];
            const float hi = (fabsf(xv) >= F16_MIN_NORM) ? xv : 0.0f;
            const _Float16 h = (_Float16)hi;
            const float r = (xv - (float)h) * 4096.0f;
            a[j] = h; b[j] = (_Float16)r;
        }
        *reinterpret_cast<h8*>(Wp1 + (size_t)gid * 8) = a;
        *reinterpret_cast<h8*>(Wp2 + (size_t)gid * 8) = b;
    }
}

// ---- gemm3: r14/r15 T4 structure; block->(br,bt,ct) remap for A L2-reuse ----
__global__ __launch_bounds__(512, 4)
void gemm3_bn_lif(const _Float16* __restrict__ A1p, const _Float16* __restrict__ A2p,
                  const _Float16* __restrict__ Wq1, const _Float16* __restrict__ Wq2,
                  const _Float16* __restrict__ Wk1, const _Float16* __restrict__ Wk2,
                  const _Float16* __restrict__ Wv1, const _Float16* __restrict__ Wv2,
                  const float* __restrict__ biq, const float* __restrict__ gaq,
                  const float* __restrict__ beq, const float* __restrict__ meq,
                  const float* __restrict__ rvq,
                  const float* __restrict__ bik, const float* __restrict__ gak,
                  const float* __restrict__ bek, const float* __restrict__ mek,
                  const float* __restrict__ rvk,
                  const float* __restrict__ biv, const float* __restrict__ gav,
                  const float* __restrict__ bev, const float* __restrict__ mev,
                  const float* __restrict__ rvv,
                  _Float16* __restrict__ oq, _Float16* __restrict__ ok,
                  _Float16* __restrict__ ov)
{
    __shared__ __align__(16) char wsm[16384];           // 2 x 8KB W dbuf; reused as v-state
    const int id = blockIdx.x;                          // 1536 blocks
    const int xcd = id & 7;
    const int j = id >> 3;                              // 0..191
    const int br = j % 3;
    const int rest = j / 3;                             // 0..63
    const int bt = xcd * 8 + (rest & 7);                // 0..63
    const int ct = rest >> 3;                           // 0..7

    const _Float16* W1 = (br == 0) ? Wq1 : (br == 1) ? Wk1 : Wv1;
    const _Float16* W2 = (br == 0) ? Wq2 : (br == 1) ? Wk2 : Wv2;
    const float* bias = (br == 0) ? biq : (br == 1) ? bik : biv;
    const float* gam  = (br == 0) ? gaq : (br == 1) ? gak : gav;
    const float* bet  = (br == 0) ? beq : (br == 1) ? bek : bev;
    const float* mea  = (br == 0) ? meq : (br == 1) ? mek : mev;
    const float* rva  = (br == 0) ? rvq : (br == 1) ? rvk : rvv;
    _Float16* out = (br == 0) ? oq : (br == 1) ? ok : ov;

    const int tid = threadIdx.x;
    const int wave = tid >> 6, lane = tid & 63;
    const int tp = wave & 1, wr = wave >> 1;
    const int rt = bt * 4 + wr;
    const int row0 = bt * 64, col0 = ct * 64;
    const int lr = lane & 15, lk = lane >> 4;

    f4 accA[2][4], accB[2][4];
    #pragma unroll
    for (int ti = 0; ti < 2; ++ti)
        #pragma unroll
        for (int ni = 0; ni < 4; ++ni) { accA[ti][ni] = (f4)0.0f; accB[ti][ni] = (f4)0.0f; }

    const _Float16* aB1 = A1p + (size_t)rt * 32768 + lane * 8;
    const _Float16* aB2 = A2p + (size_t)rt * 32768 + lane * 8;
    const int s_ = wave >> 2, q_ = wave & 3;
    const _Float16* wsrc = (s_ ? W2 : W1) + (size_t)ct * 32768 + q_ * 512 + lane * 8;
    const int wdoff = s_ * 4096 + q_ * 1024;

    auto stageW = [&](int ks, int b) {
        __builtin_amdgcn_global_load_lds(
            (const __attribute__((address_space(1))) unsigned int*)(wsrc + ks * 2048),
            (__attribute__((address_space(3))) unsigned int*)(wsm + b * 8192 + wdoff),
            16, 0, 0);
    };

    stageW(0, 0);
    h8 a1c[2], a2c[2];
    #pragma unroll
    for (int ti = 0; ti < 2; ++ti) {
        const int t = tp * 2 + ti;
        a1c[ti] = *reinterpret_cast<const h8*>(aB1 + (t * 16 + 0) * 512);
        a2c[ti] = *reinterpret_cast<const h8*>(aB2 + (t * 16 + 0) * 512);
    }
    #pragma unroll
    for (int ks = 0; ks < 16; ++ks) {
        const int buf = ks & 1;
        asm volatile("s_waitcnt vmcnt(4)" ::: "memory");
        __builtin_amdgcn_s_barrier();
        __builtin_amdgcn_sched_barrier(0);
        h8 a1n[2], a2n[2];
        if (ks < 15) {
            stageW(ks + 1, buf ^ 1);                    // post-barrier: W-ring safe
            #pragma unroll
            for (int ti = 0; ti < 2; ++ti) {            // prefetch A[ks+1]
                const int t = tp * 2 + ti;
                a1n[ti] = *reinterpret_cast<const h8*>(aB1 + (t * 16 + ks + 1) * 512);
                a2n[ti] = *reinterpret_cast<const h8*>(aB2 + (t * 16 + ks + 1) * 512);
            }
        }
        const char* wb = wsm + buf * 8192;
        #pragma unroll
        for (int ni = 0; ni < 4; ++ni) {
            const h8 wf1 = *reinterpret_cast<const h8*>(wb + ni * 1024 + lane * 16);
            const h8 wf2 = *reinterpret_cast<const h8*>(wb + 4096 + ni * 1024 + lane * 16);
            #pragma unroll
            for (int ti = 0; ti < 2; ++ti) {
                accA[ti][ni] = __builtin_amdgcn_mfma_f32_16x16x32_f16(a1c[ti], wf1, accA[ti][ni], 0, 0, 0);
                accB[ti][ni] = __builtin_amdgcn_mfma_f32_16x16x32_f16(a1c[ti], wf2, accB[ti][ni], 0, 0, 0);
                accB[ti][ni] = __builtin_amdgcn_mfma_f32_16x16x32_f16(a2c[ti], wf1, accB[ti][ni], 0, 0, 0);
            }
        }
        if (ks < 15) {
            #pragma unroll
            for (int ti = 0; ti < 2; ++ti) { a1c[ti] = a1n[ti]; a2c[ti] = a2n[ti]; }
        }
    }

    float* vst = (float*)wsm;
    float sc[4], bi[4], mn[4], be[4];
    #pragma unroll
    for (int ni = 0; ni < 4; ++ni) {
        const int c = col0 + ni * 16 + lr;
        sc[ni] = gam[c] * (1.0f / sqrtf(rva[c] + EPSf));
        bi[ni] = bias[c]; mn[ni] = mea[c]; be[ni] = bet[c];
    }
    __syncthreads();
    if (tp == 0) {
        #pragma unroll
        for (int ni = 0; ni < 4; ++ni)
            #pragma unroll
            for (int r = 0; r < 4; ++r) {
                const int rl = wr * 16 + lk * 4 + r;
                const int bn = row0 + rl;
                float vm = 0.0f;
                #pragma unroll
                for (int ti = 0; ti < 2; ++ti) {        // t = 0,1
                    const float res = accA[ti][ni][r] + INV4096 * accB[ti][ni][r];
                    const float y = ((res + bi[ni]) - mn[ni]) * sc[ni] + be[ni];
                    vm = vm + (y - vm) * 0.5f;
                    const float s = (vm >= 1.0f) ? 1.0f : 0.0f;
                    vm = (s != 0.0f) ? 0.0f : vm;
                    const int b = bn >> 9, n = bn & 511;
                    out[((((size_t)ti * B_ + b) * H_ + ct) * N_ + n) * D_ + ni * 16 + lr] =
                        (_Float16)s;
                }
                vst[rl * 64 + ni * 16 + lr] = vm;
            }
    }
    __syncthreads();
    if (tp == 1) {
        #pragma unroll
        for (int ni = 0; ni < 4; ++ni)
            #pragma unroll
            for (int r = 0; r < 4; ++r) {
                const int rl = wr * 16 + lk * 4 + r;
                const int bn = row0 + rl;
                float vm = vst[rl * 64 + ni * 16 + lr];
                #pragma unroll
                for (int ti = 0; ti < 2; ++ti) {        // t = 2,3
                    const float res = accA[ti][ni][r] + INV4096 * accB[ti][ni][r];
                    const float y = ((res + bi[ni]) - mn[ni]) * sc[ni] + be[ni];
                    vm = vm + (y - vm) * 0.5f;
                    const float s = (vm >= 1.0f) ? 1.0f : 0.0f;
                    vm = (s != 0.0f) ? 0.0f : vm;
                    const int b = bn >> 9, n = bn & 511;
                    out[((((size_t)(2 + ti) * B_ + b) * H_ + ct) * N_ + n) * D_ + ni * 16 + lr] =
                        (_Float16)s;
                }
            }
    }
}

// ---- p-GEMM: r15 proven version (512 thr, per-ks W stage, vmcnt(2)) ----
__global__ __launch_bounds__(512, 4)
void gemm_p_bn_lif(const _Float16* __restrict__ A1p,
                   const _Float16* __restrict__ Wp1, const _Float16* __restrict__ Wp2,
                   const float* __restrict__ bias, const float* __restrict__ gam,
                   const float* __restrict__ bet, const float* __restrict__ mea,
                   const float* __restrict__ rva, float* __restrict__ out_plain)
{
    __shared__ __align__(16) char wsm[16384];
    const int id = blockIdx.x;
    const int bt = (id & 7) * 8 + ((id >> 3) & 7);
    const int ct = id >> 6;
    const int tid = threadIdx.x;
    const int wave = tid >> 6, lane = tid & 63;
    const int tp = wave & 1, wr = wave >> 1;
    const int rt = bt * 4 + wr;
    const int row0 = bt * 64, col0 = ct * 64;
    const int lr = lane & 15, lk = lane >> 4;

    f4 accA[2][4], accB[2][4];
    #pragma unroll
    for (int ti = 0; ti < 2; ++ti)
        #pragma unroll
        for (int ni = 0; ni < 4; ++ni) { accA[ti][ni] = (f4)0.0f; accB[ti][ni] = (f4)0.0f; }

    const _Float16* aB1 = A1p + (size_t)rt * 32768 + lane * 8;
    const int s_ = wave >> 2, q_ = wave & 3;
    const _Float16* wsrc = (s_ ? Wp2 : Wp1) + (size_t)ct * 32768 + q_ * 512 + lane * 8;
    const int wdoff = s_ * 4096 + q_ * 1024;

    auto stageW = [&](int ks, int b) {
        __builtin_amdgcn_global_load_lds(
            (const __attribute__((address_space(1))) unsigned int*)(wsrc + ks * 2048),
            (__attribute__((address_space(3))) unsigned int*)(wsm + b * 8192 + wdoff),
            16, 0, 0);
    };

    stageW(0, 0);
    h8 a1c[2];
    #pragma unroll
    for (int ti = 0; ti < 2; ++ti) {
        const int t = tp * 2 + ti;
        a1c[ti] = *reinterpret_cast<const h8*>(aB1 + (t * 16 + 0) * 512);
    }
    #pragma unroll
    for (int ks = 0; ks < 16; ++ks) {
        const int buf = ks & 1;
        asm volatile("s_waitcnt vmcnt(2)" ::: "memory");
        __builtin_amdgcn_s_barrier();
        __builtin_amdgcn_sched_barrier(0);
        h8 a1n[2];
        if (ks < 15) {
            stageW(ks + 1, buf ^ 1);
            #pragma unroll
            for (int ti = 0; ti < 2; ++ti) {
                const int t = tp * 2 + ti;
                a1n[ti] = *reinterpret_cast<const h8*>(aB1 + (t * 16 + ks + 1) * 512);
            }
        }
        const char* wb = wsm + buf * 8192;
        #pragma unroll
        for (int ni = 0; ni < 4; ++ni) {
            const h8 wf1 = *reinterpret_cast<const h8*>(wb + ni * 1024 + lane * 16);
            const h8 wf2 = *reinterpret_cast<const h8*>(wb + 4096 + ni * 1024 + lane * 16);
            #pragma unroll
            for (int ti = 0; ti < 2; ++ti) {
                accA[ti][ni] = __builtin_amdgcn_mfma_f32_16x16x32_f16(a1c[ti], wf1, accA[ti][ni], 0, 0, 0);
                accB[ti][ni] = __builtin_amdgcn_mfma_f32_16x16x32_f16(a1c[ti], wf2, accB[ti][ni], 0, 0, 0);
            }
        }
        if (ks < 15) {
            #pragma unroll
            for (int ti = 0; ti < 2; ++ti) a1c[ti] = a1n[ti];
        }
    }

    float* vst = (float*)wsm;
    float sc[4], bi[4], mn[4], be[4];
    #pragma unroll
    for (int ni = 0; ni < 4; ++ni) {
        const int c = col0 + ni * 16 + lr;
        sc[ni] = gam[c] * (1.0f / sqrtf(rva[c] + EPSf));
        bi[ni] = bias[c]; mn[ni] = mea[c]; be[ni] = bet[c];
    }
    __syncthreads();
    if (tp == 0) {
        #pragma unroll
        for (int ni = 0; ni < 4; ++ni)
            #pragma unroll
            for (int r = 0; r < 4; ++r) {
                const int rl = wr * 16 + lk * 4 + r;
                const int bn = row0 + rl;
                float vm = 0.0f;
                #pragma unroll
                for (int ti = 0; ti < 2; ++ti) {        // t = 0,1
                    const float res = accA[ti][ni][r] + INV4096 * accB[ti][ni][r];
                    const float y = ((res + bi[ni]) - mn[ni]) * sc[ni] + be[ni];
                    vm = vm + (y - vm) * 0.5f;
                    const float s = (vm >= 1.0f) ? 1.0f : 0.0f;
                    vm = (s != 0.0f) ? 0.0f : vm;
                    out_plain[((size_t)ti * BNR + bn) * C_ + col0 + ni * 16 + lr] = s;
                }
                vst[rl * 64 + ni * 16 + lr] = vm;
            }
    }
    __syncthreads();
    if (tp == 1) {
        #pragma unroll
        for (int ni = 0; ni < 4; ++ni)
            #pragma unroll
            for (int r = 0; r < 4; ++r) {
                const int rl = wr * 16 + lk * 4 + r;
                const int bn = row0 + rl;
                float vm = vst[rl * 64 + ni * 16 + lr];
                #pragma unroll
                for (int ti = 0; ti < 2; ++ti) {        // t = 2,3
                    const float res = accA[ti][ni][r] + INV4096 * accB[ti][ni][r];
                    const float y = ((res + bi[ni]) - mn[ni]) * sc[ni] + be[ni];
                    vm = vm + (y - vm) * 0.5f;
                    const float s = (vm >= 1.0f) ? 1.0f : 0.0f;
                    vm = (s != 0.0f) ? 0.0f : vm;
                    out_plain[((size_t)(2 + ti) * BNR + bn) * C_ + col0 + ni * 16 + lr] = s;
                }
            }
    }
}

// ---- ktv via MFMA: kvT[d2][d1] = sum_n v[n,d2]*k[n,d1], exact integers ----
__global__ __launch_bounds__(256)
void ktv_mfma(const _Float16* __restrict__ sk, const _Float16* __restrict__ sv,
              _Float16* __restrict__ kvT)
{
    __shared__ _Float16 kT[64][64];
    __shared__ _Float16 vT[64][64];
    const int tbh = blockIdx.x;
    const int tid = threadIdx.x;
    const int wv = tid >> 6, lane = tid & 63;
    const int lr = lane & 15, lk = lane >> 4;
    const size_t base = (size_t)tbh * N_ * D_;

    f4 acc[4];
    #pragma unroll
    for (int ni = 0; ni < 4; ++ni) acc[ni] = (f4)0.0f;

    for (int n0 = 0; n0 < N_; n0 += 64) {
        __syncthreads();
        #pragma unroll
        for (int p = 0; p < 2; ++p) {
            const int idx = p * 256 + tid;
            const int n = idx >> 3, d0 = (idx & 7) * 8;
            const h8 kv_ = *reinterpret_cast<const h8*>(&sk[base + (size_t)(n0 + n) * D_ + d0]);
            const h8 vv_ = *reinterpret_cast<const h8*>(&sv[base + (size_t)(n0 + n) * D_ + d0]);
            #pragma unroll
            for (int j = 0; j < 8; ++j) {
                const int d = d0 + j;
                const int nsw = (((n >> 3) ^ (d & 7)) << 3) | (n & 7);
                kT[d][nsw] = kv_[j];
                vT[d][nsw] = vv_[j];
            }
        }
        __syncthreads();
        #pragma unroll
        for (int ks2 = 0; ks2 < 2; ++ks2) {
            const int g0 = ks2 * 4 + lk;
            const int d2 = wv * 16 + lr;
            const h8 av = *reinterpret_cast<const h8*>(&vT[d2][(g0 ^ (d2 & 7)) << 3]);
            #pragma unroll
            for (int ni = 0; ni < 4; ++ni) {
                const int d1 = ni * 16 + lr;
                const h8 bk = *reinterpret_cast<const h8*>(&kT[d1][(g0 ^ (d1 & 7)) << 3]);
                acc[ni] = __builtin_amdgcn_mfma_f32_16x16x32_f16(av, bk, acc[ni], 0, 0, 0);
            }
        }
    }
    _Float16* out = kvT + (size_t)tbh * 4096;
    #pragma unroll
    for (int ni = 0; ni < 4; ++ni)
        #pragma unroll
        for (int r = 0; r < 4; ++r) {
            const int d2 = wv * 16 + lk * 4 + r;
            const int d1 = ni * 16 + lr;
            out[d2 * 64 + d1] = (_Float16)acc[ni][r];
        }
}

// ---- o = 0.125 * q @ kv via MFMA (exact integer arith), fused attn-LIF ----
__global__ __launch_bounds__(256)
void qkv_mfma_lif(const _Float16* __restrict__ sq, const _Float16* __restrict__ kvT,
                  _Float16* __restrict__ osp)
{
    __shared__ __align__(16) char ot[8192];             // [64 rows][128B], swizzled
    const int nt = blockIdx.x, b = blockIdx.y, h = blockIdx.z;
    const int tid = threadIdx.x;
    const int wv = tid >> 6, lane = tid & 63;
    const int lr = lane & 15, lk = lane >> 4;
    const int n0 = nt * 64;

    f4 vst[4];
    #pragma unroll
    for (int ni = 0; ni < 4; ++ni) vst[ni] = (f4)0.0f;

    for (int t = 0; t < T_; ++t) {
        const int tbh = (t * B_ + b) * H_ + h;
        const _Float16* qb = sq + ((size_t)tbh * N_ + n0 + wv * 16 + lr) * D_;
        const h8 a0 = *reinterpret_cast<const h8*>(qb + lk * 8);
        const h8 a1 = *reinterpret_cast<const h8*>(qb + 32 + lk * 8);
        const _Float16* kb = kvT + (size_t)tbh * 4096 + lr * 64 + lk * 8;
        f4 acc[4];
        #pragma unroll
        for (int ni = 0; ni < 4; ++ni) {
            const _Float16* kbn = kb + ni * 1024;
            const h8 b0 = *reinterpret_cast<const h8*>(kbn);
            const h8 b1 = *reinterpret_cast<const h8*>(kbn + 32);
            f4 a = (f4)0.0f;
            a = __builtin_amdgcn_mfma_f32_16x16x32_f16(a0, b0, a, 0, 0, 0);
            a = __builtin_amdgcn_mfma_f32_16x16x32_f16(a1, b1, a, 0, 0, 0);
            acc[ni] = a;
        }
        #pragma unroll
        for (int ni = 0; ni < 4; ++ni)
            #pragma unroll
            for (int r = 0; r < 4; ++r) {
                const float y = 0.125f * acc[ni][r];    // exact
                float vv = vst[ni][r];
                vv = vv + (y - vv) * 0.5f;
                const float s = (vv >= 0.5f) ? 1.0f : 0.0f;
                vst[ni][r] = (s != 0.0f) ? 0.0f : vv;
                const int row = wv * 16 + lk * 4 + r;
                const int colb = (ni * 16 + lr) * 2;
                *(_Float16*)(ot + row * 128 + (colb ^ ((row & 7) << 4))) = (_Float16)s;
            }
        const int rt = b * 32 + nt * 4 + wv;
        #pragma unroll
        for (int ks1 = 0; ks1 < 2; ++ks1) {
            const int row = wv * 16 + lr;
            const int colb = ks1 * 64 + lk * 16;
            const h8 vvv = *reinterpret_cast<const h8*>(ot + row * 128 + (colb ^ ((row & 7) << 4)));
            *reinterpret_cast<h8*>(osp +
                ((((size_t)rt * 4 + t) * 16 + h * 2 + ks1) * 64 + lane) * 8) = vvv;
        }
    }
}

extern "C" void kernel_launch(void* const* d_in, const int* in_sizes, int n_in,
                              void* d_out, int out_size, void* d_ws, size_t ws_size,
                              hipStream_t stream)
{
    const float* x = (const float*)d_in[0];
    const float *W[4], *bia[4], *gam[4], *bet[4], *mea[4], *rva[4];
    for (int br = 0; br < 4; ++br) {
        W[br]   = (const float*)d_in[1 + 6 * br + 0];
        bia[br] = (const float*)d_in[1 + 6 * br + 1];
        gam[br] = (const float*)d_in[1 + 6 * br + 2];
        bet[br] = (const float*)d_in[1 + 6 * br + 3];
        mea[br] = (const float*)d_in[1 + 6 * br + 4];
        rva[br] = (const float*)d_in[1 + 6 * br + 5];
    }
    char* ws = (char*)d_ws;
    _Float16* x1 = (_Float16*)(ws + 0);
    _Float16* x2 = (_Float16*)(ws + 16777216);
    _Float16* sq = (_Float16*)(ws + 33554432);
    _Float16* sk = (_Float16*)(ws + 50331648);
    _Float16* sv = (_Float16*)(ws + 67108864);
    _Float16* w1[4], *w2[4];
    for (int br = 0; br < 4; ++br) {
        w1[br] = (_Float16*)(ws + 83886080 + (size_t)br * 1048576);
        w2[br] = (_Float16*)(ws + 83886080 + (size_t)br * 1048576 + 524288);
    }
    _Float16* kvT = (_Float16*)(ws + 16777216);  // aliases x2 (dead after gemm3)
    _Float16* osp = (_Float16*)(ws + 0);         // aliases x1 (dead after gemm3)

    dim3 blk(256);
    pack_all<<<dim3(4608), blk, 0, stream>>>(x, x1, x2,
        W[0], W[1], W[2], W[3],
        w1[0], w2[0], w1[1], w2[1], w1[2], w2[2], w1[3], w2[3]);

    gemm3_bn_lif<<<dim3(1536), dim3(512), 0, stream>>>(x1, x2,
        w1[0], w2[0], w1[1], w2[1], w1[2], w2[2],
        bia[0], gam[0], bet[0], mea[0], rva[0],
        bia[1], gam[1], bet[1], mea[1], rva[1],
        bia[2], gam[2], bet[2], mea[2], rva[2],
        sq, sk, sv);

    ktv_mfma<<<dim3(T_ * B_ * H_), blk, 0, stream>>>(sk, sv, kvT);
    qkv_mfma_lif<<<dim3(N_ / 64, B_, H_), blk, 0, stream>>>(sq, kvT, osp);

    gemm_p_bn_lif<<<dim3(512), dim3(512), 0, stream>>>(osp, w1[3], w2[3],
        bia[3], gam[3], bet[3], mea[3], rva[3], (float*)d_out);
}